// Round 2
// 754.448 us; speedup vs baseline: 1.2006x; 1.2006x over previous
//
#include <hip/hip_runtime.h>

// ============================================================================
// WeightPopupLayer (fp32 I/O): out = x @ (W * topk_mask(|scores|, 50%))^T + b
//   x[8192,4096] f32, W[4096,4096] f32, bias[4096] f32, scores[4096,4096] f32
//   out[8192,4096] f32.
// Selection: exact 4-pass radix select + stable tie ranking (unchanged, passed).
// GEMM: upgraded m97 128^2 structure -> 256^2 8-wave 4-phase counted-vmcnt
// schedule (T2 swizzle + T3/T4 counted vmcnt + T5 setprio + T1 XCD swizzle).
// Accumulation order over K identical to previous kernel (same K=32 chain).
// ============================================================================

#define NTOT   16777216u    // 4096*4096
#define JDROP  8388608u     // int((1-K)*n), K=0.5
#define MDIM   8192
#define NDIM   4096
#define KDIM   4096

typedef __bf16 v8bf __attribute__((ext_vector_type(8)));
typedef float  v4f  __attribute__((ext_vector_type(4)));

__device__ __forceinline__ unsigned short f2bf(float f){
  unsigned u = __float_as_uint(f);
  u += 0x7fffu + ((u >> 16) & 1u);   // RNE
  return (unsigned short)(u >> 16);
}

// ---------------------------------------------------------------------------
// 4-pass radix select over u = bits(|s|) & 0x7FFFFFFF (monotonic in value).
// ---------------------------------------------------------------------------
__global__ void zero_hist(unsigned* hist){ hist[threadIdx.x] = 0u; }

__global__ __launch_bounds__(256) void hist_pass(const float* __restrict__ scores,
                                                 unsigned* __restrict__ hist,
                                                 const unsigned* __restrict__ state,
                                                 int p){
  // per-thread privatized byte counters pc[digit*256 + tid]; max 64/thread.
  __shared__ __align__(16) unsigned char pc[256*256];   // 64 KB
  int tid = threadIdx.x;
  unsigned* pz = (unsigned*)pc;
  #pragma unroll
  for (int k=0;k<64;++k) pz[tid + k*256] = 0u;
  __syncthreads();
  unsigned prefix = (p>0) ? state[0] : 0u;
  const float4* s4 = (const float4*)(scores + (size_t)blockIdx.x * 16384);
  for (int it=0; it<16; ++it){
    float4 v = s4[(size_t)it*256 + tid];
    #pragma unroll
    for (int e=0;e<4;++e){
      float f = (e==0)?v.x:(e==1)?v.y:(e==2)?v.z:v.w;
      unsigned u = __float_as_uint(f) & 0x7fffffffu;
      unsigned d, ok;
      if      (p==0){ d = u>>23;         ok = 1u; }
      else if (p==1){ d = (u>>15)&0xffu; ok = ((u>>23)==prefix); }
      else if (p==2){ d = (u>>7) &0xffu; ok = ((u>>15)==prefix); }
      else          { d = u & 0x7fu;     ok = ((u>>7) ==prefix); }
      if (ok) pc[d*256 + tid]++;
    }
  }
  __syncthreads();
  unsigned b = (unsigned)tid;          // bin b: sum 256 byte-columns
  const unsigned* row = (const unsigned*)(pc + b*256);
  unsigned s = 0;
  for (int kk=0;kk<64;++kk){
    int k = (kk + tid) & 63;           // stagger LDS banks
    unsigned w = row[k];
    s += (w & 0xffu) + ((w>>8)&0xffu) + ((w>>16)&0xffu) + (w>>24);
  }
  if (s) atomicAdd(&hist[b], s);
}

__global__ void select_pass(unsigned* hist, unsigned* state, int p){
  int lane = threadIdx.x;              // 64 threads = 1 wave
  unsigned c[4];
  #pragma unroll
  for (int k=0;k<4;++k){ c[k] = hist[lane*4+k]; hist[lane*4+k] = 0u; }
  unsigned s = c[0]+c[1]+c[2]+c[3];
  unsigned inc = s;
  #pragma unroll
  for (int d=1; d<64; d<<=1){
    unsigned t = (unsigned)__shfl_up((int)inc, d, 64);
    if (lane >= d) inc += t;
  }
  unsigned excl = inc - s;
  unsigned target = (p==0) ? JDROP : state[1];
  unsigned oldpre = (p==0) ? 0u    : state[0];
  if (target >= excl && target < excl + s){   // unique crossing lane
    unsigned cum = excl, digit = 0, below = 0;
    #pragma unroll
    for (int k=0;k<4;++k){
      if (target < cum + c[k]){ digit = (unsigned)lane*4u + (unsigned)k; below = cum; break; }
      cum += c[k];
    }
    state[0] = (oldpre << ((p==3)?7:8)) | digit;
    state[1] = target - below;
  }
}

// ---------------------------------------------------------------------------
// Stable tie ranking: per-4096-chunk tie counts -> scan -> flat-order rank.
// ---------------------------------------------------------------------------
__global__ __launch_bounds__(256) void tie_count(const float* __restrict__ scores,
                                                 const unsigned* __restrict__ state,
                                                 unsigned* __restrict__ tieCnt){
  unsigned T = state[0];
  int tid = threadIdx.x;
  const float4* s4 = (const float4*)(scores + (size_t)blockIdx.x * 4096);
  unsigned cnt = 0;
  for (int it=0; it<4; ++it){
    float4 v = s4[it*256 + tid];
    #pragma unroll
    for (int e=0;e<4;++e){
      float f = (e==0)?v.x:(e==1)?v.y:(e==2)?v.z:v.w;
      unsigned u = __float_as_uint(f) & 0x7fffffffu;
      cnt += (u == T) ? 1u : 0u;
    }
  }
  __shared__ unsigned r[256];
  r[tid] = cnt; __syncthreads();
  for (int s=128; s>0; s>>=1){ if (tid < s) r[tid] += r[tid+s]; __syncthreads(); }
  if (tid==0) tieCnt[blockIdx.x] = r[0];
}

__global__ __launch_bounds__(1024) void tie_scan(const unsigned* tieCnt, unsigned* tieBase){
  int tid = threadIdx.x;               // 1024 threads, 4 chunks each
  unsigned v[4], pre[4], s = 0;
  #pragma unroll
  for (int k=0;k<4;++k){ v[k] = tieCnt[tid*4+k]; pre[k] = s; s += v[k]; }
  __shared__ unsigned sc[1024];
  sc[tid] = s; __syncthreads();
  for (int d=1; d<1024; d<<=1){
    unsigned t = (tid >= d) ? sc[tid-d] : 0u;
    __syncthreads();
    sc[tid] += t;
    __syncthreads();
  }
  unsigned excl = sc[tid] - s;
  #pragma unroll
  for (int k=0;k<4;++k) tieBase[tid*4+k] = excl + pre[k];
}

__global__ __launch_bounds__(256) void build_pruned(const float* __restrict__ scores,
                                                    const float* __restrict__ w,
                                                    const unsigned* __restrict__ state,
                                                    const unsigned* __restrict__ tieBase,
                                                    unsigned short* __restrict__ wpr){
  int c = blockIdx.x;                  // one 4096-elem chunk (= one W row)
  int tid = threadIdx.x;
  int lane = tid & 63, wid = tid >> 6;
  unsigned T = state[0], D = state[1];
  __shared__ unsigned wcnt[4];
  __shared__ unsigned runBase;
  if (tid==0) runBase = tieBase[c];
  size_t base = (size_t)c * 4096;
  for (int it=0; it<16; ++it){
    size_t i = base + it*256 + tid;    // flat-order traversal
    unsigned u = __float_as_uint(scores[i]) & 0x7fffffffu;
    bool tie = (u == T), gt = (u > T);
    unsigned long long b = __ballot(tie);
    unsigned lanePre = (unsigned)__popcll(b & ((1ull << lane) - 1ull));
    if (lane==0) wcnt[wid] = (unsigned)__popcll(b);
    __syncthreads();                   // wcnt ready; runBase stable
    unsigned off = 0;
    #pragma unroll
    for (int ww=0; ww<4; ++ww) if (ww < wid) off += wcnt[ww];
    unsigned tot = wcnt[0]+wcnt[1]+wcnt[2]+wcnt[3];
    unsigned rank = runBase + off + lanePre;   // global flat-order tie rank
    bool keep = gt || (tie && rank >= D);      // first D ties dropped
    wpr[i] = keep ? f2bf(w[i]) : (unsigned short)0;
    __syncthreads();                   // all reads of runBase done
    if (tid==0) runBase += tot;
  }
}

// ---------------------------------------------------------------------------
// x fp32 -> bf16
// ---------------------------------------------------------------------------
__global__ __launch_bounds__(256) void convert_x(const float4* __restrict__ x,
                                                 ushort4* __restrict__ xb){
  size_t i = (size_t)blockIdx.x * 256 + threadIdx.x;   // one float4 each
  float4 v = x[i];
  ushort4 o; o.x=f2bf(v.x); o.y=f2bf(v.y); o.z=f2bf(v.z); o.w=f2bf(v.w);
  xb[i] = o;
}

// ---------------------------------------------------------------------------
// GEMM: out[m,n] = sum_k xb[m,k]*wpr[n,k] + bias[n]; fp32 out.
// 256x256 tile, BK=64, 8 waves (2Mx4N), per-wave 128x64 output.
// LDS 128 KiB: As/Bs[2][256][64] bf16, double-buffered at K-tile granularity.
// Swizzle: LDS slot (row, c16) holds global col16 (c16 ^ (row&7)); staging
// keeps global_load_lds dest LINEAR and pre-swizzles the per-lane global
// source address; ds_read applies the same XOR (both-sides rule).
// Schedule per K-tile t (buffer q = t&1), prefetch tile t+2 into buf q:
//   P0: ds_read a0 (A m0-3, 8xb128) + b0 (B n0-1, 4) | bar | lgkm0 | Q0 | bar
//   P1: ds_read b1 (B n2-3, 4)                       | bar | lgkm0 | Q1 | bar
//   P2: ds_read a1 (A m4-7, 8); issue stage B(t+2)   | bar | lgkm0 | Q2 | bar
//   P3: issue stage A(t+2); Q3; s_waitcnt vmcnt(8) (drains tile t+1) | bar
// Legality: B(t+2) lands in Bs[q] only after all waves' B reads of tile t
// completed (P1-end barrier); A(t+2) after P2-end barrier. vmcnt(8) keeps
// tile t+2's 8 loads in flight across the barrier (never drains to 0 in
// steady state).
// ---------------------------------------------------------------------------
__device__ __forceinline__ void gload_lds16b(const void* g, void* l){
  __builtin_amdgcn_global_load_lds(
      (__attribute__((address_space(1))) void*)g,
      (__attribute__((address_space(3))) void*)l, 16, 0, 0);
}

// stage both 128-row halves of one matrix's K-tile (4 x 16B loads / thread)
__device__ __forceinline__ void stage_mat(const unsigned short* __restrict__ G, int rowBase,
                                          unsigned short (* __restrict__ S)[64],
                                          int kt, int wid, int lane){
  #pragma unroll
  for (int hj=0; hj<4; ++hj){                              // h = hj>>1, j = hj&1
    const int rg0 = (hj>>1)*128 + (wid*2 + (hj&1))*8;      // wave-uniform row base
    const int rg  = rg0 + (lane>>3);                       // this lane's row
    const int c16 = (lane&7) ^ (rg & 7);                   // inverse-swizzled src col
    gload_lds16b(G + (size_t)(rowBase + rg)*KDIM + kt*64 + c16*8, &S[rg0][0]);
  }
}

__device__ __forceinline__ v8bf ldsfrag(const unsigned short (* __restrict__ S)[64],
                                        int row, int kc){
  return *(const v8bf*)&S[row][(kc ^ (row & 7))*8];
}

#define BAR()   { __builtin_amdgcn_s_barrier(); asm volatile("" ::: "memory"); }
#define LGKM0() asm volatile("s_waitcnt lgkmcnt(0)" ::: "memory")

__device__ __forceinline__ void ktile(const unsigned short* __restrict__ A,
                                      const unsigned short* __restrict__ B,
                                      unsigned short (* __restrict__ Asq)[64],
                                      unsigned short (* __restrict__ Bsq)[64],
                                      int Mb, int Nb, int t,
                                      int wr, int wc, int wid, int lane,
                                      v4f acc[8][4]){
  const int r16 = lane & 15, kg = lane >> 4;
  const bool pf = (t + 2 < KDIM/64);

  // ---- P0: A m0-3 + B n0-1 reads; Q0 = acc[0..3][0..1]
  v8bf a0[4][2], b0[2][2];
  #pragma unroll
  for (int i=0;i<4;++i)
    #pragma unroll
    for (int ks=0;ks<2;++ks)
      a0[i][ks] = ldsfrag(Asq, wr*128 + i*16 + r16, ks*4 + kg);
  #pragma unroll
  for (int n=0;n<2;++n)
    #pragma unroll
    for (int ks=0;ks<2;++ks)
      b0[n][ks] = ldsfrag(Bsq, wc*64 + n*16 + r16, ks*4 + kg);
  BAR(); LGKM0();
  __builtin_amdgcn_s_setprio(1);
  #pragma unroll
  for (int i=0;i<4;++i)
    #pragma unroll
    for (int n=0;n<2;++n)
      #pragma unroll
      for (int ks=0;ks<2;++ks)
        acc[i][n] = __builtin_amdgcn_mfma_f32_16x16x32_bf16(a0[i][ks], b0[n][ks], acc[i][n], 0,0,0);
  __builtin_amdgcn_s_setprio(0);
  BAR();

  // ---- P1: B n2-3 reads; Q1 = acc[0..3][2..3] (a0 x b1)
  v8bf b1[2][2];
  #pragma unroll
  for (int n=0;n<2;++n)
    #pragma unroll
    for (int ks=0;ks<2;++ks)
      b1[n][ks] = ldsfrag(Bsq, wc*64 + (2+n)*16 + r16, ks*4 + kg);
  BAR(); LGKM0();
  __builtin_amdgcn_s_setprio(1);
  #pragma unroll
  for (int i=0;i<4;++i)
    #pragma unroll
    for (int n=0;n<2;++n)
      #pragma unroll
      for (int ks=0;ks<2;++ks)
        acc[i][2+n] = __builtin_amdgcn_mfma_f32_16x16x32_bf16(a0[i][ks], b1[n][ks], acc[i][2+n], 0,0,0);
  __builtin_amdgcn_s_setprio(0);
  BAR();   // all waves' B reads of tile t complete past this point

  // ---- P2: A m4-7 reads; issue stage B(t+2); Q2 = acc[4..7][0..1] (a1 x b0)
  v8bf a1[4][2];
  #pragma unroll
  for (int i=0;i<4;++i)
    #pragma unroll
    for (int ks=0;ks<2;++ks)
      a1[i][ks] = ldsfrag(Asq, wr*128 + 64 + i*16 + r16, ks*4 + kg);
  if (pf) stage_mat(B, Nb, Bsq, t+2, wid, lane);
  BAR(); LGKM0();
  __builtin_amdgcn_s_setprio(1);
  #pragma unroll
  for (int i=0;i<4;++i)
    #pragma unroll
    for (int n=0;n<2;++n)
      #pragma unroll
      for (int ks=0;ks<2;++ks)
        acc[4+i][n] = __builtin_amdgcn_mfma_f32_16x16x32_bf16(a1[i][ks], b0[n][ks], acc[4+i][n], 0,0,0);
  __builtin_amdgcn_s_setprio(0);
  BAR();   // all waves' A reads of tile t complete past this point

  // ---- P3: issue stage A(t+2); Q3 = acc[4..7][2..3] (a1 x b1); drain t+1
  if (pf) stage_mat(A, Mb, Asq, t+2, wid, lane);
  __builtin_amdgcn_s_setprio(1);
  #pragma unroll
  for (int i=0;i<4;++i)
    #pragma unroll
    for (int n=0;n<2;++n)
      #pragma unroll
      for (int ks=0;ks<2;++ks)
        acc[4+i][2+n] = __builtin_amdgcn_mfma_f32_16x16x32_bf16(a1[i][ks], b1[n][ks], acc[4+i][2+n], 0,0,0);
  __builtin_amdgcn_s_setprio(0);
  if (pf) { asm volatile("s_waitcnt vmcnt(8)" ::: "memory"); }
  else    { asm volatile("s_waitcnt vmcnt(0)" ::: "memory"); }
  BAR();   // tile t+1 fully resident for every wave past this point
}

__global__ __launch_bounds__(512, 2) void gemm256(const unsigned short* __restrict__ A, // xb bf16 [M,K]
                                                  const unsigned short* __restrict__ B, // wpr bf16 [N,K]
                                                  const float* __restrict__ bias,
                                                  float* __restrict__ out){
  __shared__ __align__(16) unsigned short As[2][256][64];  // 64 KB
  __shared__ __align__(16) unsigned short Bs[2][256][64];  // 64 KB

  // T1: XCD-aware swizzle. 512 wgs, 8 XCDs, 64 contiguous per XCD.
  const int bid = blockIdx.x;
  const int swz = (bid & 7) * 64 + (bid >> 3);
  const int Mb  = (swz >> 4) * 256;    // 32 M-tiles
  const int Nb  = (swz & 15) * 256;    // 16 N-tiles

  const int tid  = threadIdx.x;
  const int lane = tid & 63;
  const int wid  = tid >> 6;           // 0..7
  const int wr   = wid >> 2;           // 0..1 (M)
  const int wc   = wid & 3;            // 0..3 (N)

  v4f acc[8][4];
  #pragma unroll
  for (int i=0;i<8;++i)
    #pragma unroll
    for (int n=0;n<4;++n) acc[i][n] = (v4f){0.f,0.f,0.f,0.f};

  // prologue: stage tiles 0 and 1 (16 loads), land tile 0, keep tile 1 in flight
  stage_mat(A, Mb, As[0], 0, wid, lane);
  stage_mat(B, Nb, Bs[0], 0, wid, lane);
  stage_mat(A, Mb, As[1], 1, wid, lane);
  stage_mat(B, Nb, Bs[1], 1, wid, lane);
  asm volatile("s_waitcnt vmcnt(8)" ::: "memory");
  BAR();

  #pragma unroll 1
  for (int t = 0; t < KDIM/64; t += 2){
    ktile(A, B, As[0], Bs[0], Mb, Nb, t,   wr, wc, wid, lane, acc);
    ktile(A, B, As[1], Bs[1], Mb, Nb, t+1, wr, wc, wid, lane, acc);
  }

  // epilogue: C/D layout col(n) = lane&15, row(m) = (lane>>4)*4 + r
  #pragma unroll
  for (int mt=0; mt<8; ++mt){
    const int gm0 = Mb + wr*128 + mt*16 + (lane >> 4)*4;
    #pragma unroll
    for (int nt=0; nt<4; ++nt){
      const int gn = Nb + wc*64 + nt*16 + (lane & 15);
      const float bv = bias[gn];
      v4f a = acc[mt][nt];
      #pragma unroll
      for (int r=0; r<4; ++r)
        out[(size_t)(gm0 + r)*NDIM + gn] = a[r] + bv;
    }
  }
}

// ---------------------------------------------------------------------------
extern "C" void kernel_launch(void* const* d_in, const int* in_sizes, int n_in,
                              void* d_out, int out_size, void* d_ws, size_t ws_size,
                              hipStream_t stream){
  const float* x      = (const float*)d_in[0];
  const float* w      = (const float*)d_in[1];
  const float* bias   = (const float*)d_in[2];
  const float* scores = (const float*)d_in[3];
  float* out = (float*)d_out;

  char* ws = (char*)d_ws;
  unsigned* hist    = (unsigned*)(ws);                 // 1 KB
  unsigned* state   = (unsigned*)(ws + 1024);          // {prefix/T, target/D}
  unsigned* tieCnt  = (unsigned*)(ws + 2048);          // 16 KB
  unsigned* tieBase = (unsigned*)(ws + 2048 + 16384);  // 16 KB
  unsigned short* xb  = (unsigned short*)(ws + 65536);              // 64 MB
  unsigned short* wpr = (unsigned short*)(ws + 65536 + (size_t)MDIM*KDIM*2); // 32 MB

  zero_hist<<<1, 256, 0, stream>>>(hist);
  for (int p = 0; p < 4; ++p){
    hist_pass<<<1024, 256, 0, stream>>>(scores, hist, state, p);
    select_pass<<<1, 64, 0, stream>>>(hist, state, p);
  }
  tie_count<<<4096, 256, 0, stream>>>(scores, state, tieCnt);
  tie_scan<<<1, 1024, 0, stream>>>(tieCnt, tieBase);
  build_pruned<<<4096, 256, 0, stream>>>(scores, w, state, tieBase, wpr);
  convert_x<<<MDIM*KDIM/4/256, 256, 0, stream>>>((const float4*)x, (ushort4*)xb);

  gemm256<<<dim3(512), 512, 0, stream>>>(xb, wpr, bias, out);
}